// Round 10
// baseline (290.002 us; speedup 1.0000x reference)
//
#include <hip/hip_runtime.h>
#include <math.h>

#define NN 50000
#define NE 1000000

typedef __bf16 bf16x8 __attribute__((ext_vector_type(8)));
typedef float f32x4 __attribute__((ext_vector_type(4)));

__device__ inline unsigned short f2bf(float f) {          // fp32 -> bf16 RNE
    unsigned u = __float_as_uint(f);
    u += 0x7FFFu + ((u >> 16) & 1u);
    return (unsigned short)(u >> 16);
}
__device__ inline float bf2f(unsigned short s) {
    return __uint_as_float(((unsigned)s) << 16);
}
__device__ inline float bflo(unsigned r) { return __uint_as_float(r << 16); }
__device__ inline float bfhi(unsigned r) { return __uint_as_float(r & 0xffff0000u); }

// ---- prep: W1 -> Bt1[64][320] bf16 (zero-pad k>=300), W2 -> Bt2[64][64] bf16 ----
__global__ __launch_bounds__(256) void prep_B(const float* __restrict__ W1,
        const float* __restrict__ W2, unsigned short* __restrict__ Bt1,
        unsigned short* __restrict__ Bt2)
{
    int t = blockIdx.x * 256 + threadIdx.x;        // grid = 96 blocks = 24576 exactly
    if (t < 64 * 320) {
        int c = t / 320, k = t % 320;
        Bt1[t] = (k < 300) ? f2bf(W1[k * 64 + c]) : (unsigned short)0;
    } else {
        int i = t - 64 * 320;
        int c = i >> 6, k = i & 63;
        Bt2[i] = f2bf(W2[k * 64 + c]);
    }
}

// ---- MFMA GEMM: C[M,64] = A[M,K] @ B, bf16 mfma, fused bf16-h store + logits ----
template <int HEADS, bool A_IS_F32>
__global__ __launch_bounds__(256) void gemm_mfma(const void* __restrict__ Av,
        const unsigned short* __restrict__ Bt,    // [64][KT*32] bf16
        unsigned short* __restrict__ hb,
        const float* __restrict__ asrc, const float* __restrict__ adst,
        float* __restrict__ ss, float* __restrict__ sd,
        int M, int K, int KT)
{
    __shared__ unsigned short lds[5120];           // As[64][40] | Bs[64][40]; reused as Ct
    const int tid  = threadIdx.x;
    const int row0 = blockIdx.x * 64;
    const int lane = tid & 63, w = tid >> 6;
    const int quad = lane >> 4, mm = lane & 15;
    const int sr = tid >> 2, q8 = (tid & 3) * 8;   // staging row / k-octet
    const int gsr = row0 + sr;

    f32x4 acc[4];
    #pragma unroll
    for (int i = 0; i < 4; ++i) acc[i] = (f32x4){0.f, 0.f, 0.f, 0.f};

    const int Kpad = KT * 32;
    for (int kt = 0; kt < KT; ++kt) {
        const int k0 = kt * 32;
        // ---- stage A (64 x 32) ----
        int4 apack = {0, 0, 0, 0};
        if (gsr < M) {
            if (A_IS_F32) {
                const float* A = (const float*)Av;
                const float* ap = A + (size_t)gsr * K + k0 + q8;
                unsigned short* up = (unsigned short*)&apack;
                if (k0 + q8 + 7 < K) {
                    float4 v0 = *(const float4*)ap;
                    float4 v1 = *(const float4*)(ap + 4);
                    up[0]=f2bf(v0.x); up[1]=f2bf(v0.y); up[2]=f2bf(v0.z); up[3]=f2bf(v0.w);
                    up[4]=f2bf(v1.x); up[5]=f2bf(v1.y); up[6]=f2bf(v1.z); up[7]=f2bf(v1.w);
                } else {
                    #pragma unroll
                    for (int j = 0; j < 8; ++j)
                        up[j] = (k0 + q8 + j < K) ? f2bf(ap[j]) : (unsigned short)0;
                }
            } else {
                const unsigned short* A = (const unsigned short*)Av;
                apack = *(const int4*)(A + (size_t)gsr * K + k0 + q8);
            }
        }
        *(int4*)(lds + sr * 40 + q8) = apack;
        // ---- stage B (64 cols x 32 k) from pre-transposed Bt: direct copy ----
        *(int4*)(lds + 2560 + sr * 40 + q8) =
            *(const int4*)(Bt + (size_t)sr * Kpad + k0 + q8);
        __syncthreads();
        // ---- MFMA: A[m=lane&15][k=quad*8+j], B[k=quad*8+j][n=lane&15] ----
        bf16x8 af = *(const bf16x8*)(lds + (w * 16 + mm) * 40 + quad * 8);
        #pragma unroll
        for (int nt = 0; nt < 4; ++nt) {
            bf16x8 bfv = *(const bf16x8*)(lds + 2560 + (nt * 16 + mm) * 40 + quad * 8);
            acc[nt] = __builtin_amdgcn_mfma_f32_16x16x32_bf16(af, bfv, acc[nt], 0, 0, 0);
        }
        __syncthreads();
    }
    // ---- epilogue: C (col=lane&15, row=quad*4+reg) -> LDS bf16 tile ----
    #pragma unroll
    for (int nt = 0; nt < 4; ++nt)
        #pragma unroll
        for (int reg = 0; reg < 4; ++reg)
            lds[w * 1152 + (quad * 4 + reg) * 72 + nt * 16 + mm] = f2bf(acc[nt][reg]);
    __syncthreads();
    // coalesced bf16 h store: 16 shorts (32 B) per thread = TWO int4 stores
    const int cg = (tid & 3) * 16;
    const unsigned short* crow = lds + (sr >> 4) * 1152 + (sr & 15) * 72;
    if (gsr < M) {
        *(int4*)(hb + (size_t)gsr * 64 + cg)     = *(const int4*)(crow + cg);
        *(int4*)(hb + (size_t)gsr * 64 + cg + 8) = *(const int4*)(crow + cg + 8);
    }
    if (HEADS == 8) {
        #pragma unroll
        for (int hh = 0; hh < 2; ++hh) {
            int hd = (tid & 3) + hh * 4;
            float pss = 0.f, psd = 0.f;
            #pragma unroll
            for (int c = 0; c < 8; ++c) {
                float hv = bf2f(crow[hd * 8 + c]);
                pss += hv * asrc[hd * 8 + c];
                psd += hv * adst[hd * 8 + c];
            }
            if (gsr < M) { ss[gsr * 8 + hd] = pss; sd[gsr * 8 + hd] = psd; }
        }
    } else {
        int p = tid & 3;
        float pss = 0.f, psd = 0.f;
        #pragma unroll
        for (int c = 0; c < 16; ++c) {
            float hv = bf2f(crow[p * 16 + c]);
            pss += hv * asrc[p * 16 + c];
            psd += hv * adst[p * 16 + c];
        }
        pss += __shfl_xor(pss, 1); psd += __shfl_xor(psd, 1);
        pss += __shfl_xor(pss, 2); psd += __shfl_xor(psd, 2);
        if (p == 0 && gsr < M) { ss[gsr] = pss; sd[gsr] = psd; }
    }
}

// ------ CSR: count + rank, 4 edges/thread (4 independent atomic chains) ------
__global__ __launch_bounds__(256) void count_k(const int* __restrict__ ei,
        int* __restrict__ cnt, unsigned char* __restrict__ pos)
{
    int e = (blockIdx.x * 256 + threadIdx.x) * 4;   // NE % 4 == 0
    if (e >= NE) return;
    int4 d = *(const int4*)(ei + NE + e);
    int p0 = atomicAdd(&cnt[d.x], 1);
    int p1 = atomicAdd(&cnt[d.y], 1);
    int p2 = atomicAdd(&cnt[d.z], 1);
    int p3 = atomicAdd(&cnt[d.w], 1);
    uchar4 pk;
    pk.x = (unsigned char)p0; pk.y = (unsigned char)p1;
    pk.z = (unsigned char)p2; pk.w = (unsigned char)p3;
    *(uchar4*)(pos + e) = pk;
}

// ------------- scan stage 1 -------------
__global__ __launch_bounds__(1024) void scan1(const int* __restrict__ cnt,
        int* __restrict__ excl, int* __restrict__ sums)
{
    __shared__ int buf[1024];
    int tid = threadIdx.x;
    int i = blockIdx.x * 1024 + tid;
    int v = (i < NN) ? cnt[i] : 0;
    buf[tid] = v;
    __syncthreads();
    #pragma unroll
    for (int off = 1; off < 1024; off <<= 1) {
        int t = (tid >= off) ? buf[tid - off] : 0;
        __syncthreads();
        buf[tid] += t;
        __syncthreads();
    }
    if (i < NN) excl[i] = buf[tid] - v;
    if (tid == 1023) sums[blockIdx.x] = buf[1023];
}

// ------------- scan stage 2 -------------
__global__ __launch_bounds__(64) void scan2(int* __restrict__ sums, int nb)
{
    int lane = threadIdx.x;
    int v = (lane < nb) ? sums[lane] : 0;
    int inc = v;
    #pragma unroll
    for (int off = 1; off < 64; off <<= 1) {
        int t = __shfl_up(inc, off);
        if (lane >= off) inc += t;
    }
    if (lane < nb) sums[lane] = inc - v;
}

// ------------- scan stage 3 -------------
__global__ __launch_bounds__(1024) void scan3(const int* __restrict__ excl,
        const int* __restrict__ sums, int* __restrict__ rowptr)
{
    int i = blockIdx.x * 1024 + threadIdx.x;
    if (i < NN) rowptr[i] = excl[i] + sums[blockIdx.x];
    if (i == 0) rowptr[NN] = NE;
}

// ------ CSR: scatter, 4 edges/thread (4 independent gather+store chains) ------
__global__ __launch_bounds__(256) void scatter_k(const int* __restrict__ ei,
        const int* __restrict__ rowptr, const unsigned char* __restrict__ pos,
        unsigned short* __restrict__ col)
{
    int e = (blockIdx.x * 256 + threadIdx.x) * 4;   // NE % 4 == 0
    if (e >= NE) return;
    int4 s = *(const int4*)(ei + e);
    int4 d = *(const int4*)(ei + NE + e);
    uchar4 p = *(const uchar4*)(pos + e);
    int r0 = rowptr[d.x], r1 = rowptr[d.y], r2 = rowptr[d.z], r3 = rowptr[d.w];
    __builtin_nontemporal_store((unsigned short)s.x, &col[r0 + p.x]);
    __builtin_nontemporal_store((unsigned short)s.y, &col[r1 + p.y]);
    __builtin_nontemporal_store((unsigned short)s.z, &col[r2 + p.z]);
    __builtin_nontemporal_store((unsigned short)s.w, &col[r3 + p.w]);
}

#define LEAKY(s) ((s) > 0.f ? (s) : 0.2f * (s))

// ------- layer1 agg: wave/node, 8 edges in flight (4 slots x 2-deep unroll) -------
__global__ __launch_bounds__(256) void agg_l1(const int* __restrict__ rowptr,
        const unsigned short* __restrict__ col, const unsigned short* __restrict__ hb,
        const float* __restrict__ ss, const float* __restrict__ sd,
        const float* __restrict__ b, unsigned short* __restrict__ out)
{
    int n = (blockIdx.x * 256 + threadIdx.x) >> 6;
    int lane = threadIdx.x & 63;
    if (n >= NN) return;
    const int es = lane >> 4;            // edge slot 0..3
    const int cg = (lane & 15) << 2;     // channel group base
    const int hd = cg >> 3;              // head
    float sdst = sd[n * 8 + hd];
    int r0 = rowptr[n], r1 = rowptr[n + 1];
    f32x4 acc = {0.f, 0.f, 0.f, 0.f};
    float dsum = 0.f;
    for (int i = r0; i < r1; i += 8) {
        int e0 = i + es, e1 = i + 4 + es;
        bool v0 = e0 < r1, v1 = e1 < r1;
        int a0 = (int)col[v0 ? e0 : r0];
        int a1 = (int)col[v1 ? e1 : r0];
        // issue both independent chains back-to-back (MLP=2 per wave, 8 edges)
        uint2 ra = *(const uint2*)(hb + a0 * 64 + cg);
        uint2 rb = *(const uint2*)(hb + a1 * 64 + cg);
        float sa = ss[a0 * 8 + hd];
        float sb = ss[a1 * 8 + hd];
        float w0 = v0 ? __expf(LEAKY(sa + sdst)) : 0.f;
        float w1 = v1 ? __expf(LEAKY(sb + sdst)) : 0.f;
        acc[0] += w0 * bflo(ra.x) + w1 * bflo(rb.x);
        acc[1] += w0 * bfhi(ra.x) + w1 * bfhi(rb.x);
        acc[2] += w0 * bflo(ra.y) + w1 * bflo(rb.y);
        acc[3] += w0 * bfhi(ra.y) + w1 * bfhi(rb.y);
        dsum += w0 + w1;
    }
    #pragma unroll
    for (int m = 16; m <= 32; m <<= 1) {
        acc[0] += __shfl_xor(acc[0], m); acc[1] += __shfl_xor(acc[1], m);
        acc[2] += __shfl_xor(acc[2], m); acc[3] += __shfl_xor(acc[3], m);
        dsum += __shfl_xor(dsum, m);
    }
    if (es == 0) {
        float inv = 1.f / (dsum + 1e-16f);
        float v0 = acc[0] * inv + b[cg + 0]; v0 = v0 > 0.f ? v0 : expm1f(v0);
        float v1 = acc[1] * inv + b[cg + 1]; v1 = v1 > 0.f ? v1 : expm1f(v1);
        float v2 = acc[2] * inv + b[cg + 2]; v2 = v2 > 0.f ? v2 : expm1f(v2);
        float v3 = acc[3] * inv + b[cg + 3]; v3 = v3 > 0.f ? v3 : expm1f(v3);
        unsigned o01 = (unsigned)f2bf(v0) | ((unsigned)f2bf(v1) << 16);
        unsigned o23 = (unsigned)f2bf(v2) | ((unsigned)f2bf(v3) << 16);
        *(uint2*)(out + n * 64 + cg) = make_uint2(o01, o23);
    }
}

// ------- layer2 agg: wave/node, 8 edges in flight, fp32 out -------
__global__ __launch_bounds__(256) void agg_l2(const int* __restrict__ rowptr,
        const unsigned short* __restrict__ col, const unsigned short* __restrict__ hb,
        const float* __restrict__ ss, const float* __restrict__ sd,
        const float* __restrict__ b, float* __restrict__ out)
{
    int n = (blockIdx.x * 256 + threadIdx.x) >> 6;
    int lane = threadIdx.x & 63;
    if (n >= NN) return;
    const int es = lane >> 4;
    const int cg = (lane & 15) << 2;
    float sdst = sd[n];
    int r0 = rowptr[n], r1 = rowptr[n + 1];
    f32x4 acc = {0.f, 0.f, 0.f, 0.f};
    float dsum = 0.f;
    for (int i = r0; i < r1; i += 8) {
        int e0 = i + es, e1 = i + 4 + es;
        bool v0 = e0 < r1, v1 = e1 < r1;
        int a0 = (int)col[v0 ? e0 : r0];
        int a1 = (int)col[v1 ? e1 : r0];
        uint2 ra = *(const uint2*)(hb + a0 * 64 + cg);
        uint2 rb = *(const uint2*)(hb + a1 * 64 + cg);
        float sa = ss[a0];
        float sb = ss[a1];
        float w0 = v0 ? __expf(LEAKY(sa + sdst)) : 0.f;
        float w1 = v1 ? __expf(LEAKY(sb + sdst)) : 0.f;
        acc[0] += w0 * bflo(ra.x) + w1 * bflo(rb.x);
        acc[1] += w0 * bfhi(ra.x) + w1 * bfhi(rb.x);
        acc[2] += w0 * bflo(ra.y) + w1 * bflo(rb.y);
        acc[3] += w0 * bfhi(ra.y) + w1 * bfhi(rb.y);
        dsum += w0 + w1;
    }
    #pragma unroll
    for (int m = 16; m <= 32; m <<= 1) {
        acc[0] += __shfl_xor(acc[0], m); acc[1] += __shfl_xor(acc[1], m);
        acc[2] += __shfl_xor(acc[2], m); acc[3] += __shfl_xor(acc[3], m);
        dsum += __shfl_xor(dsum, m);
    }
    if (es == 0) {
        float inv = 1.f / (dsum + 1e-16f);
        float4 o;
        o.x = acc[0] * inv + b[cg + 0];
        o.y = acc[1] * inv + b[cg + 1];
        o.z = acc[2] * inv + b[cg + 2];
        o.w = acc[3] * inv + b[cg + 3];
        *(float4*)(out + n * 64 + cg) = o;
    }
}

extern "C" void kernel_launch(void* const* d_in, const int* in_sizes, int n_in,
                              void* d_out, int out_size, void* d_ws, size_t ws_size,
                              hipStream_t stream)
{
    const float* x      = (const float*)d_in[0];
    const int*   ei     = (const int*)d_in[1];
    const float* W1     = (const float*)d_in[2];
    const float* a_src1 = (const float*)d_in[3];
    const float* a_dst1 = (const float*)d_in[4];
    const float* b1     = (const float*)d_in[5];
    const float* W2     = (const float*)d_in[6];
    const float* a_src2 = (const float*)d_in[7];
    const float* a_dst2 = (const float*)d_in[8];
    const float* b2     = (const float*)d_in[9];
    float* out = (float*)d_out;

    // workspace (16B-aligned blocks first)
    char* wp = (char*)d_ws;
    unsigned short* hb  = (unsigned short*)wp;  wp += (size_t)NN * 64 * 2;  // h1 then h2 (bf16)
    unsigned short* P1b = (unsigned short*)wp;  wp += (size_t)NN * 64 * 2;  // h2in (bf16)
    unsigned short* Bt1 = (unsigned short*)wp;  wp += (size_t)64 * 320 * 2; // W1^T bf16 padded
    unsigned short* Bt2 = (unsigned short*)wp;  wp += (size_t)64 * 64 * 2;  // W2^T bf16
    float* ss1 = (float*)wp;  wp += (size_t)NN * 8 * 4;
    float* sd1 = (float*)wp;  wp += (size_t)NN * 8 * 4;
    int* cnt    = (int*)wp;  wp += (size_t)NN * 4;
    int* excl   = (int*)wp;  wp += (size_t)NN * 4;
    int* sums   = (int*)wp;  wp += 64 * 4;
    int* rowptr = (int*)wp;  wp += (size_t)(NN + 1) * 4;
    unsigned short* col = (unsigned short*)wp;  wp += (size_t)(NE + 8) * 2;
    unsigned char*  pos = (unsigned char*)wp;   wp += (size_t)NE;
    float* ss2 = ss1;                    // alias (layer1 logits dead in layer2)
    float* sd2 = ss1 + NN;

    const int NB = (NN + 1023) / 1024;

    // ---- CSR build + weight prep ----
    hipMemsetAsync(cnt, 0, NN * sizeof(int), stream);
    count_k<<<(NE / 4 + 255) / 256, 256, 0, stream>>>(ei, cnt, pos);
    scan1<<<NB, 1024, 0, stream>>>(cnt, excl, sums);
    scan2<<<1, 64, 0, stream>>>(sums, NB);
    scan3<<<NB, 1024, 0, stream>>>(excl, sums, rowptr);
    scatter_k<<<(NE / 4 + 255) / 256, 256, 0, stream>>>(ei, rowptr, pos, col);
    prep_B<<<96, 256, 0, stream>>>(W1, W2, Bt1, Bt2);

    // ---- layer 1 ----
    gemm_mfma<8, true><<<(NN + 63) / 64, 256, 0, stream>>>(
        x, Bt1, hb, a_src1, a_dst1, ss1, sd1, NN, 300, 10);
    agg_l1<<<(NN * 64 + 255) / 256, 256, 0, stream>>>(rowptr, col, hb, ss1, sd1, b1, P1b);

    // ---- layer 2 ----
    gemm_mfma<1, false><<<(NN + 63) / 64, 256, 0, stream>>>(
        P1b, Bt2, hb, a_src2, a_dst2, ss2, sd2, NN, 64, 2);
    agg_l2<<<(NN * 64 + 255) / 256, 256, 0, stream>>>(rowptr, col, hb, ss2, sd2, b2, out);
}

// Round 11
// 281.880 us; speedup vs baseline: 1.0288x; 1.0288x over previous
//
#include <hip/hip_runtime.h>
#include <math.h>

#define NN 50000
#define NE 1000000
#define NCB 977          // count blocks: ceil(NE/1024)
#define NGB 782          // gemm L1 blocks: ceil(NN/64)

typedef __bf16 bf16x8 __attribute__((ext_vector_type(8)));
typedef float f32x4 __attribute__((ext_vector_type(4)));

__device__ inline unsigned short f2bf(float f) {          // fp32 -> bf16 RNE
    unsigned u = __float_as_uint(f);
    u += 0x7FFFu + ((u >> 16) & 1u);
    return (unsigned short)(u >> 16);
}
__device__ inline float bf2f(unsigned short s) {
    return __uint_as_float(((unsigned)s) << 16);
}
__device__ inline float bflo(unsigned r) { return __uint_as_float(r << 16); }
__device__ inline float bfhi(unsigned r) { return __uint_as_float(r & 0xffff0000u); }

// ---- prep: W1->Bt1[64][320] bf16 pad, W2->Bt2[64][64] bf16, zero cnt ----
__global__ __launch_bounds__(256) void prep_init(const float* __restrict__ W1,
        const float* __restrict__ W2, unsigned short* __restrict__ Bt1,
        unsigned short* __restrict__ Bt2, int* __restrict__ cnt)
{
    int bid = blockIdx.x;
    if (bid < 96) {
        int t = bid * 256 + threadIdx.x;           // 96*256 = 24576 = 64*320+64*64
        if (t < 64 * 320) {
            int c = t / 320, k = t % 320;
            Bt1[t] = (k < 300) ? f2bf(W1[k * 64 + c]) : (unsigned short)0;
        } else {
            int i = t - 64 * 320;
            int c = i >> 6, k = i & 63;
            Bt2[i] = f2bf(W2[k * 64 + c]);
        }
    } else {                                        // blocks [96,160): zero cnt
        int idx = (bid - 96) * 256 + threadIdx.x;
        for (int i = idx; i < NN; i += 64 * 256) cnt[i] = 0;
    }
}

// ---- FAT kernel: blocks [0,NCB) = CSR count (atomic-wall-bound, ~0% VALU)
//                  blocks [NCB,NCB+NGB) = L1 MFMA GEMM (rides under the wall) ----
__global__ __launch_bounds__(256) void k1_count_gemm(
        const int* __restrict__ ei, int* __restrict__ cnt,
        unsigned char* __restrict__ pos,
        const float* __restrict__ A, const unsigned short* __restrict__ Bt,
        unsigned short* __restrict__ hb,
        const float* __restrict__ asrc, const float* __restrict__ adst,
        float* __restrict__ ss, float* __restrict__ sd)
{
    __shared__ unsigned short lds[5120];           // used by gemm blocks only
    const int tid = threadIdx.x;

    if (blockIdx.x < NCB) {
        // ---------------- count body: 4 edges/thread ----------------
        int e = (blockIdx.x * 256 + tid) * 4;      // NE % 4 == 0
        if (e >= NE) return;
        int4 d = *(const int4*)(ei + NE + e);
        int p0 = atomicAdd(&cnt[d.x], 1);
        int p1 = atomicAdd(&cnt[d.y], 1);
        int p2 = atomicAdd(&cnt[d.z], 1);
        int p3 = atomicAdd(&cnt[d.w], 1);
        uchar4 pk;
        pk.x = (unsigned char)p0; pk.y = (unsigned char)p1;
        pk.z = (unsigned char)p2; pk.w = (unsigned char)p3;
        *(uchar4*)(pos + e) = pk;
        return;
    }

    // ---------------- gemm body (HEADS=8, A fp32, K=300, KT=10) ----------------
    const int row0 = (blockIdx.x - NCB) * 64;
    const int lane = tid & 63, w = tid >> 6;
    const int quad = lane >> 4, mm = lane & 15;
    const int sr = tid >> 2, q8 = (tid & 3) * 8;
    const int gsr = row0 + sr;
    const int K = 300, KT = 10, Kpad = 320, M = NN;

    f32x4 acc[4];
    #pragma unroll
    for (int i = 0; i < 4; ++i) acc[i] = (f32x4){0.f, 0.f, 0.f, 0.f};

    for (int kt = 0; kt < KT; ++kt) {
        const int k0 = kt * 32;
        int4 apack = {0, 0, 0, 0};
        if (gsr < M) {
            const float* ap = A + (size_t)gsr * K + k0 + q8;
            unsigned short* up = (unsigned short*)&apack;
            if (k0 + q8 + 7 < K) {
                float4 v0 = *(const float4*)ap;
                float4 v1 = *(const float4*)(ap + 4);
                up[0]=f2bf(v0.x); up[1]=f2bf(v0.y); up[2]=f2bf(v0.z); up[3]=f2bf(v0.w);
                up[4]=f2bf(v1.x); up[5]=f2bf(v1.y); up[6]=f2bf(v1.z); up[7]=f2bf(v1.w);
            } else {
                #pragma unroll
                for (int j = 0; j < 8; ++j)
                    up[j] = (k0 + q8 + j < K) ? f2bf(ap[j]) : (unsigned short)0;
            }
        }
        *(int4*)(lds + sr * 40 + q8) = apack;
        *(int4*)(lds + 2560 + sr * 40 + q8) =
            *(const int4*)(Bt + (size_t)sr * Kpad + k0 + q8);
        __syncthreads();
        bf16x8 af = *(const bf16x8*)(lds + (w * 16 + mm) * 40 + quad * 8);
        #pragma unroll
        for (int nt = 0; nt < 4; ++nt) {
            bf16x8 bfv = *(const bf16x8*)(lds + 2560 + (nt * 16 + mm) * 40 + quad * 8);
            acc[nt] = __builtin_amdgcn_mfma_f32_16x16x32_bf16(af, bfv, acc[nt], 0, 0, 0);
        }
        __syncthreads();
    }
    // epilogue: C (col=lane&15, row=quad*4+reg) -> LDS bf16 tile
    #pragma unroll
    for (int nt = 0; nt < 4; ++nt)
        #pragma unroll
        for (int reg = 0; reg < 4; ++reg)
            lds[w * 1152 + (quad * 4 + reg) * 72 + nt * 16 + mm] = f2bf(acc[nt][reg]);
    __syncthreads();
    const int cg = (tid & 3) * 16;
    const unsigned short* crow = lds + (sr >> 4) * 1152 + (sr & 15) * 72;
    if (gsr < M) {
        *(int4*)(hb + (size_t)gsr * 64 + cg)     = *(const int4*)(crow + cg);
        *(int4*)(hb + (size_t)gsr * 64 + cg + 8) = *(const int4*)(crow + cg + 8);
    }
    #pragma unroll
    for (int hh = 0; hh < 2; ++hh) {
        int hd = (tid & 3) + hh * 4;
        float pss = 0.f, psd = 0.f;
        #pragma unroll
        for (int c = 0; c < 8; ++c) {
            float hv = bf2f(crow[hd * 8 + c]);
            pss += hv * asrc[hd * 8 + c];
            psd += hv * adst[hd * 8 + c];
        }
        if (gsr < M) { ss[gsr * 8 + hd] = pss; sd[gsr * 8 + hd] = psd; }
    }
}

// ---- MFMA GEMM for layer 2 (A bf16, HEADS=1, K=64, KT=2), fused h+logits ----
__global__ __launch_bounds__(256) void gemm_l2(const unsigned short* __restrict__ A,
        const unsigned short* __restrict__ Bt, unsigned short* __restrict__ hb,
        const float* __restrict__ asrc, const float* __restrict__ adst,
        float* __restrict__ ss, float* __restrict__ sd)
{
    __shared__ unsigned short lds[5120];
    const int tid  = threadIdx.x;
    const int row0 = blockIdx.x * 64;
    const int lane = tid & 63, w = tid >> 6;
    const int quad = lane >> 4, mm = lane & 15;
    const int sr = tid >> 2, q8 = (tid & 3) * 8;
    const int gsr = row0 + sr;
    const int K = 64, KT = 2, Kpad = 64, M = NN;

    f32x4 acc[4];
    #pragma unroll
    for (int i = 0; i < 4; ++i) acc[i] = (f32x4){0.f, 0.f, 0.f, 0.f};

    for (int kt = 0; kt < KT; ++kt) {
        const int k0 = kt * 32;
        int4 apack = {0, 0, 0, 0};
        if (gsr < M) apack = *(const int4*)(A + (size_t)gsr * K + k0 + q8);
        *(int4*)(lds + sr * 40 + q8) = apack;
        *(int4*)(lds + 2560 + sr * 40 + q8) =
            *(const int4*)(Bt + (size_t)sr * Kpad + k0 + q8);
        __syncthreads();
        bf16x8 af = *(const bf16x8*)(lds + (w * 16 + mm) * 40 + quad * 8);
        #pragma unroll
        for (int nt = 0; nt < 4; ++nt) {
            bf16x8 bfv = *(const bf16x8*)(lds + 2560 + (nt * 16 + mm) * 40 + quad * 8);
            acc[nt] = __builtin_amdgcn_mfma_f32_16x16x32_bf16(af, bfv, acc[nt], 0, 0, 0);
        }
        __syncthreads();
    }
    #pragma unroll
    for (int nt = 0; nt < 4; ++nt)
        #pragma unroll
        for (int reg = 0; reg < 4; ++reg)
            lds[w * 1152 + (quad * 4 + reg) * 72 + nt * 16 + mm] = f2bf(acc[nt][reg]);
    __syncthreads();
    const int cg = (tid & 3) * 16;
    const unsigned short* crow = lds + (sr >> 4) * 1152 + (sr & 15) * 72;
    if (gsr < M) {
        *(int4*)(hb + (size_t)gsr * 64 + cg)     = *(const int4*)(crow + cg);
        *(int4*)(hb + (size_t)gsr * 64 + cg + 8) = *(const int4*)(crow + cg + 8);
    }
    int p = tid & 3;
    float pss = 0.f, psd = 0.f;
    #pragma unroll
    for (int c = 0; c < 16; ++c) {
        float hv = bf2f(crow[p * 16 + c]);
        pss += hv * asrc[p * 16 + c];
        psd += hv * adst[p * 16 + c];
    }
    pss += __shfl_xor(pss, 1); psd += __shfl_xor(psd, 1);
    pss += __shfl_xor(pss, 2); psd += __shfl_xor(psd, 2);
    if (p == 0 && gsr < M) { ss[gsr] = pss; sd[gsr] = psd; }
}

// ------------- scan stage 1 -------------
__global__ __launch_bounds__(1024) void scan1(const int* __restrict__ cnt,
        int* __restrict__ excl, int* __restrict__ sums)
{
    __shared__ int buf[1024];
    int tid = threadIdx.x;
    int i = blockIdx.x * 1024 + tid;
    int v = (i < NN) ? cnt[i] : 0;
    buf[tid] = v;
    __syncthreads();
    #pragma unroll
    for (int off = 1; off < 1024; off <<= 1) {
        int t = (tid >= off) ? buf[tid - off] : 0;
        __syncthreads();
        buf[tid] += t;
        __syncthreads();
    }
    if (i < NN) excl[i] = buf[tid] - v;
    if (tid == 1023) sums[blockIdx.x] = buf[1023];
}

// ------------- scan stage 2+3 merged: each block scans 49 sums redundantly -------------
__global__ __launch_bounds__(1024) void scan23(const int* __restrict__ excl,
        const int* __restrict__ sums, int* __restrict__ rowptr)
{
    int off = 0;
    for (int j = 0; j < (int)blockIdx.x; ++j) off += sums[j];   // uniform scalar loop
    int i = blockIdx.x * 1024 + threadIdx.x;
    if (i < NN) rowptr[i] = excl[i] + off;
    if (i == 0) rowptr[NN] = NE;
}

// ------ CSR: scatter, 4 edges/thread (4 independent gather+store chains) ------
__global__ __launch_bounds__(256) void scatter_k(const int* __restrict__ ei,
        const int* __restrict__ rowptr, const unsigned char* __restrict__ pos,
        unsigned short* __restrict__ col)
{
    int e = (blockIdx.x * 256 + threadIdx.x) * 4;   // NE % 4 == 0
    if (e >= NE) return;
    int4 s = *(const int4*)(ei + e);
    int4 d = *(const int4*)(ei + NE + e);
    uchar4 p = *(const uchar4*)(pos + e);
    int r0 = rowptr[d.x], r1 = rowptr[d.y], r2 = rowptr[d.z], r3 = rowptr[d.w];
    __builtin_nontemporal_store((unsigned short)s.x, &col[r0 + p.x]);
    __builtin_nontemporal_store((unsigned short)s.y, &col[r1 + p.y]);
    __builtin_nontemporal_store((unsigned short)s.z, &col[r2 + p.z]);
    __builtin_nontemporal_store((unsigned short)s.w, &col[r3 + p.w]);
}

#define LEAKY(s) ((s) > 0.f ? (s) : 0.2f * (s))

// ------- layer1 agg: wave/node, 8 edges in flight (4 slots x 2-deep unroll) -------
__global__ __launch_bounds__(256) void agg_l1(const int* __restrict__ rowptr,
        const unsigned short* __restrict__ col, const unsigned short* __restrict__ hb,
        const float* __restrict__ ss, const float* __restrict__ sd,
        const float* __restrict__ b, unsigned short* __restrict__ out)
{
    int n = (blockIdx.x * 256 + threadIdx.x) >> 6;
    int lane = threadIdx.x & 63;
    if (n >= NN) return;
    const int es = lane >> 4;            // edge slot 0..3
    const int cg = (lane & 15) << 2;     // channel group base
    const int hd = cg >> 3;              // head
    float sdst = sd[n * 8 + hd];
    int r0 = rowptr[n], r1 = rowptr[n + 1];
    f32x4 acc = {0.f, 0.f, 0.f, 0.f};
    float dsum = 0.f;
    for (int i = r0; i < r1; i += 8) {
        int e0 = i + es, e1 = i + 4 + es;
        bool v0 = e0 < r1, v1 = e1 < r1;
        int a0 = (int)col[v0 ? e0 : r0];
        int a1 = (int)col[v1 ? e1 : r0];
        uint2 ra = *(const uint2*)(hb + a0 * 64 + cg);
        uint2 rb = *(const uint2*)(hb + a1 * 64 + cg);
        float sa = ss[a0 * 8 + hd];
        float sb = ss[a1 * 8 + hd];
        float w0 = v0 ? __expf(LEAKY(sa + sdst)) : 0.f;
        float w1 = v1 ? __expf(LEAKY(sb + sdst)) : 0.f;
        acc[0] += w0 * bflo(ra.x) + w1 * bflo(rb.x);
        acc[1] += w0 * bfhi(ra.x) + w1 * bfhi(rb.x);
        acc[2] += w0 * bflo(ra.y) + w1 * bflo(rb.y);
        acc[3] += w0 * bfhi(ra.y) + w1 * bfhi(rb.y);
        dsum += w0 + w1;
    }
    #pragma unroll
    for (int m = 16; m <= 32; m <<= 1) {
        acc[0] += __shfl_xor(acc[0], m); acc[1] += __shfl_xor(acc[1], m);
        acc[2] += __shfl_xor(acc[2], m); acc[3] += __shfl_xor(acc[3], m);
        dsum += __shfl_xor(dsum, m);
    }
    if (es == 0) {
        float inv = 1.f / (dsum + 1e-16f);
        float v0 = acc[0] * inv + b[cg + 0]; v0 = v0 > 0.f ? v0 : expm1f(v0);
        float v1 = acc[1] * inv + b[cg + 1]; v1 = v1 > 0.f ? v1 : expm1f(v1);
        float v2 = acc[2] * inv + b[cg + 2]; v2 = v2 > 0.f ? v2 : expm1f(v2);
        float v3 = acc[3] * inv + b[cg + 3]; v3 = v3 > 0.f ? v3 : expm1f(v3);
        unsigned o01 = (unsigned)f2bf(v0) | ((unsigned)f2bf(v1) << 16);
        unsigned o23 = (unsigned)f2bf(v2) | ((unsigned)f2bf(v3) << 16);
        *(uint2*)(out + n * 64 + cg) = make_uint2(o01, o23);
    }
}

// ------- layer2 agg: wave/node, 8 edges in flight, fp32 out -------
__global__ __launch_bounds__(256) void agg_l2(const int* __restrict__ rowptr,
        const unsigned short* __restrict__ col, const unsigned short* __restrict__ hb,
        const float* __restrict__ ss, const float* __restrict__ sd,
        const float* __restrict__ b, float* __restrict__ out)
{
    int n = (blockIdx.x * 256 + threadIdx.x) >> 6;
    int lane = threadIdx.x & 63;
    if (n >= NN) return;
    const int es = lane >> 4;
    const int cg = (lane & 15) << 2;
    float sdst = sd[n];
    int r0 = rowptr[n], r1 = rowptr[n + 1];
    f32x4 acc = {0.f, 0.f, 0.f, 0.f};
    float dsum = 0.f;
    for (int i = r0; i < r1; i += 8) {
        int e0 = i + es, e1 = i + 4 + es;
        bool v0 = e0 < r1, v1 = e1 < r1;
        int a0 = (int)col[v0 ? e0 : r0];
        int a1 = (int)col[v1 ? e1 : r0];
        uint2 ra = *(const uint2*)(hb + a0 * 64 + cg);
        uint2 rb = *(const uint2*)(hb + a1 * 64 + cg);
        float sa = ss[a0];
        float sb = ss[a1];
        float w0 = v0 ? __expf(LEAKY(sa + sdst)) : 0.f;
        float w1 = v1 ? __expf(LEAKY(sb + sdst)) : 0.f;
        acc[0] += w0 * bflo(ra.x) + w1 * bflo(rb.x);
        acc[1] += w0 * bfhi(ra.x) + w1 * bfhi(rb.x);
        acc[2] += w0 * bflo(ra.y) + w1 * bflo(rb.y);
        acc[3] += w0 * bfhi(ra.y) + w1 * bfhi(rb.y);
        dsum += w0 + w1;
    }
    #pragma unroll
    for (int m = 16; m <= 32; m <<= 1) {
        acc[0] += __shfl_xor(acc[0], m); acc[1] += __shfl_xor(acc[1], m);
        acc[2] += __shfl_xor(acc[2], m); acc[3] += __shfl_xor(acc[3], m);
        dsum += __shfl_xor(dsum, m);
    }
    if (es == 0) {
        float inv = 1.f / (dsum + 1e-16f);
        float4 o;
        o.x = acc[0] * inv + b[cg + 0];
        o.y = acc[1] * inv + b[cg + 1];
        o.z = acc[2] * inv + b[cg + 2];
        o.w = acc[3] * inv + b[cg + 3];
        *(float4*)(out + n * 64 + cg) = o;
    }
}

extern "C" void kernel_launch(void* const* d_in, const int* in_sizes, int n_in,
                              void* d_out, int out_size, void* d_ws, size_t ws_size,
                              hipStream_t stream)
{
    const float* x      = (const float*)d_in[0];
    const int*   ei     = (const int*)d_in[1];
    const float* W1     = (const float*)d_in[2];
    const float* a_src1 = (const float*)d_in[3];
    const float* a_dst1 = (const float*)d_in[4];
    const float* b1     = (const float*)d_in[5];
    const float* W2     = (const float*)d_in[6];
    const float* a_src2 = (const float*)d_in[7];
    const float* a_dst2 = (const float*)d_in[8];
    const float* b2     = (const float*)d_in[9];
    float* out = (float*)d_out;

    // workspace (16B-aligned blocks first)
    char* wp = (char*)d_ws;
    unsigned short* hb  = (unsigned short*)wp;  wp += (size_t)NN * 64 * 2;  // h1 then h2 (bf16)
    unsigned short* P1b = (unsigned short*)wp;  wp += (size_t)NN * 64 * 2;  // h2in (bf16)
    unsigned short* Bt1 = (unsigned short*)wp;  wp += (size_t)64 * 320 * 2; // W1^T bf16 padded
    unsigned short* Bt2 = (unsigned short*)wp;  wp += (size_t)64 * 64 * 2;  // W2^T bf16
    float* ss1 = (float*)wp;  wp += (size_t)NN * 8 * 4;
    float* sd1 = (float*)wp;  wp += (size_t)NN * 8 * 4;
    int* cnt    = (int*)wp;  wp += (size_t)NN * 4;
    int* excl   = (int*)wp;  wp += (size_t)NN * 4;
    int* sums   = (int*)wp;  wp += 64 * 4;
    int* rowptr = (int*)wp;  wp += (size_t)(NN + 1) * 4;
    unsigned short* col = (unsigned short*)wp;  wp += (size_t)(NE + 8) * 2;
    unsigned char*  pos = (unsigned char*)wp;   wp += (size_t)NE;
    float* ss2 = ss1;                    // alias (layer1 logits dead in layer2)
    float* sd2 = ss1 + NN;

    const int NB = (NN + 1023) / 1024;   // 49

    // prep weights + zero cnt (one dispatch)
    prep_init<<<160, 256, 0, stream>>>(W1, W2, Bt1, Bt2, cnt);
    // FAT: CSR count (blocks 0..976)  ||  L1 GEMM (blocks 977..1758)
    k1_count_gemm<<<NCB + NGB, 256, 0, stream>>>(
        ei, cnt, pos, x, Bt1, hb, a_src1, a_dst1, ss1, sd1);
    scan1<<<NB, 1024, 0, stream>>>(cnt, excl, sums);
    scan23<<<NB, 1024, 0, stream>>>(excl, sums, rowptr);
    scatter_k<<<(NE / 4 + 255) / 256, 256, 0, stream>>>(ei, rowptr, pos, col);

    agg_l1<<<(NN * 64 + 255) / 256, 256, 0, stream>>>(rowptr, col, hb, ss1, sd1, b1, P1b);
    gemm_l2<<<(NN + 63) / 64, 256, 0, stream>>>(P1b, Bt2, hb, a_src2, a_dst2, ss2, sd2);
    agg_l2<<<(NN * 64 + 255) / 256, 256, 0, stream>>>(rowptr, col, hb, ss2, sd2, b2, out);
}